// Round 4
// baseline (174.737 us; speedup 1.0000x reference)
//
#include <hip/hip_runtime.h>
#include <hip/hip_bf16.h>

// out = base + (base @ A2.T) @ bb.T  where A2 = M.T @ A, M = B.T @ diag(e) @ aa.T  (16x16)
// base [N=16384 rows][D=4096], A[16][4096], E[32], B[32][16], aa[16][32], bb[4096][16]
// Fused: each block owns 64 rows end-to-end. Phase A: t[64][16] = rows @ A2t
// (lane=row, swizzled LDS staging, wave-uniform A2t s_loads). Phase B: out =
// base + t @ bb.T (lane=4 cols, bb in regs, t broadcast from LDS; base re-read
// hits L2/L3 since this block just streamed it).

#define D_DIM 4096
#define K_LR 16
#define R_LR 32
#define ROWS 64        // rows per block
#define NW 8           // waves per block (512 threads)
#define WWIN 512       // per-wave col window in phase A
#define DC 32          // cols staged per chunk (128 B per row)
#define NCH (WWIN / DC)    // 16 chunks
#define BWIN 2048      // per-window cols in phase B (512 thr * 4)
#define NBW (D_DIM / BWIN) // 2 windows

typedef float f32x4 __attribute__((ext_vector_type(4)));

__global__ void __launch_bounds__(256) prep_kernel(const float* __restrict__ A,
                                                   const float* __restrict__ E,
                                                   const float* __restrict__ Bm,
                                                   const float* __restrict__ aa,
                                                   float* __restrict__ A2t) {
    __shared__ float Ms[K_LR][K_LR];
    const int t = threadIdx.x;
    {
        const int k = t >> 4, kp = t & 15;
        float s = 0.f;
        #pragma unroll
        for (int r = 0; r < R_LR; ++r)
            s += Bm[r * K_LR + k] * E[r] * aa[kp * R_LR + r];
        Ms[k][kp] = s;  // M[k][k'] = sum_r B[r][k] * e[r] * aa[k'][r]
    }
    __syncthreads();
    const int d = blockIdx.x * 256 + t;
    float acc[K_LR];
    #pragma unroll
    for (int kp = 0; kp < K_LR; ++kp) acc[kp] = 0.f;
    #pragma unroll
    for (int k = 0; k < K_LR; ++k) {
        const float a = A[k * D_DIM + d];
        #pragma unroll
        for (int kp = 0; kp < K_LR; ++kp) acc[kp] = fmaf(a, Ms[k][kp], acc[kp]);
    }
    #pragma unroll
    for (int kq = 0; kq < 4; ++kq) {
        f32x4 v = { acc[kq*4+0], acc[kq*4+1], acc[kq*4+2], acc[kq*4+3] };
        *(f32x4*)(A2t + (size_t)d * K_LR + kq * 4) = v;  // A2t[d][k'] d-major
    }
}

__global__ void __launch_bounds__(512) fused_kernel(const float* __restrict__ base,
                                                    const float* __restrict__ A2t,
                                                    const float* __restrict__ bb,
                                                    float* __restrict__ out, int N) {
    __shared__ float stage[NW][ROWS][DC];     // 64 KiB, per-wave 8 KiB quadrants
    __shared__ float tred[ROWS][NW][K_LR];    // 32 KiB wave partials
    __shared__ float tfin[ROWS][K_LR];        // 4 KiB final t
    const int tid  = threadIdx.x;
    const int lane = tid & 63;
    const int wv   = __builtin_amdgcn_readfirstlane(tid >> 6);
    const int r0   = blockIdx.x * ROWS;

    // ---------------- Phase A: t = rows @ A2t (barrier-free per wave) -------
    {
        const int a = lane >> 3;            // row-within-8-group for staging
        const int b = lane & 7;             // col4-group for staging
        const int d0 = wv * WWIN;
        char* wbase = (char*)&stage[wv][0][0];
        const int swz_w = 16 * (b ^ a);     // swizzled 16B slot for staging write
        const int swz_r = (lane & 7) << 4;  // read-side XOR (row = lane)

        float acc[K_LR];
        #pragma unroll
        for (int k = 0; k < K_LR; ++k) acc[k] = 0.f;

        f32x4 st[8];
        #pragma unroll
        for (int i = 0; i < 8; ++i)
            st[i] = *(const f32x4*)(base + (size_t)(r0 + i*8 + a) * D_DIM + d0 + 4*b);

        for (int c = 0; c < NCH; ++c) {
            #pragma unroll
            for (int i = 0; i < 8; ++i)
                *(f32x4*)(wbase + (i*8 + a) * 128 + swz_w) = st[i];
            if (c + 1 < NCH) {
                const int dcn = d0 + (c + 1) * DC;
                #pragma unroll
                for (int i = 0; i < 8; ++i)
                    st[i] = *(const f32x4*)(base + (size_t)(r0 + i*8 + a) * D_DIM + dcn + 4*b);
            }
            const int dc = d0 + c * DC;
            #pragma unroll
            for (int j = 0; j < DC/4; ++j) {
                const f32x4 b4 = *(const f32x4*)(wbase + lane * 128 + ((16*j) ^ swz_r));
                const float* a2p = A2t + (size_t)(dc + 4*j) * K_LR;  // uniform -> s_load
                #pragma unroll
                for (int jj = 0; jj < 4; ++jj) {
                    const float bv = b4[jj];
                    #pragma unroll
                    for (int k = 0; k < K_LR; ++k)
                        acc[k] = fmaf(bv, a2p[jj * K_LR + k], acc[k]);
                }
            }
        }
        #pragma unroll
        for (int kq = 0; kq < 4; ++kq) {
            f32x4 v = { acc[kq*4+0], acc[kq*4+1], acc[kq*4+2], acc[kq*4+3] };
            *(f32x4*)(&tred[lane][wv][kq * 4]) = v;
        }
    }
    __syncthreads();
    // reduce 8 wave partials -> tfin
    {
        const int r = tid >> 3, kk = (tid & 7) * 2;
        float s0 = 0.f, s1 = 0.f;
        #pragma unroll
        for (int w = 0; w < NW; ++w) {
            s0 += tred[r][w][kk];
            s1 += tred[r][w][kk + 1];
        }
        tfin[r][kk] = s0;
        tfin[r][kk + 1] = s1;
    }
    __syncthreads();

    // ---------------- Phase B: out = base + t @ bb.T ------------------------
    for (int w = NBW - 1; w >= 0; --w) {       // reverse: hottest cols first
        const int cbase = w * BWIN + tid * 4;  // this thread's 4 cols
        f32x4 bbr[4][4];
        #pragma unroll
        for (int q = 0; q < 4; ++q)
            #pragma unroll
            for (int kq = 0; kq < 4; ++kq)
                bbr[q][kq] = *(const f32x4*)(bb + (size_t)(cbase + q) * K_LR + kq * 4);

        #pragma unroll 2
        for (int r = 0; r < ROWS; ++r) {
            f32x4 t16[4];
            #pragma unroll
            for (int kq = 0; kq < 4; ++kq)
                t16[kq] = *(const f32x4*)(&tfin[r][kq * 4]);  // uniform broadcast

            const size_t row = (size_t)(r0 + r);
            const f32x4 bv = *(const f32x4*)(base + row * D_DIM + cbase);
            f32x4 ov;
            #pragma unroll
            for (int q = 0; q < 4; ++q) {
                float o = bv[q];
                #pragma unroll
                for (int k = 0; k < K_LR; ++k)
                    o = fmaf(t16[k >> 2][k & 3], bbr[q][k >> 2][k & 3], o);
                ov[q] = o;
            }
            __builtin_nontemporal_store(ov, (f32x4*)(out + row * D_DIM + cbase));
        }
    }
}

extern "C" void kernel_launch(void* const* d_in, const int* in_sizes, int n_in,
                              void* d_out, int out_size, void* d_ws, size_t ws_size,
                              hipStream_t stream) {
    const float* base = (const float*)d_in[0];
    const float* A    = (const float*)d_in[1];
    const float* E    = (const float*)d_in[2];
    const float* Bm   = (const float*)d_in[3];
    const float* aa   = (const float*)d_in[4];
    const float* bb   = (const float*)d_in[5];
    float* out = (float*)d_out;
    const int N = in_sizes[0] / D_DIM;  // 16384 rows

    float* A2t = (float*)d_ws;          // 256 KiB

    prep_kernel<<<D_DIM / 256, 256, 0, stream>>>(A, E, Bm, aa, A2t);
    fused_kernel<<<N / ROWS, 512, 0, stream>>>(base, A2t, bb, out, N);
}

// Round 5
// 147.530 us; speedup vs baseline: 1.1844x; 1.1844x over previous
//
#include <hip/hip_runtime.h>
#include <hip/hip_bf16.h>

// out = base + (base @ A2.T) @ bb.T  where A2 = M.T @ A, M = B.T @ diag(e) @ aa.T  (16x16)
// base [N=16384 rows][D=4096], A[16][4096], E[32], B[32][16], aa[16][32], bb[4096][16]
// Fused, 1024-thread blocks (16 waves = 4/SIMD for latency hiding), 1 block/CU.
// Phase A: t[64][16] = rows @ A2t (lane=row, swizzled LDS staging, uniform s_loads).
// tred aliased into stage LDS (union) to fit 132 KiB < 160 KiB.
// Phase B: out = base + t @ bb.T (thread=4 cols, bb in regs, t broadcast; base
// re-read hits L2/L3).

#define D_DIM 4096
#define K_LR 16
#define R_LR 32
#define ROWS 64        // rows per block
#define NW 16          // waves per block (1024 threads)
#define WWIN 256       // per-wave col window in phase A
#define DC 32          // cols staged per chunk (128 B per row)
#define NCH (WWIN / DC)    // 8 chunks

typedef float f32x4 __attribute__((ext_vector_type(4)));

__global__ void __launch_bounds__(256) prep_kernel(const float* __restrict__ A,
                                                   const float* __restrict__ E,
                                                   const float* __restrict__ Bm,
                                                   const float* __restrict__ aa,
                                                   float* __restrict__ A2t) {
    __shared__ float Ms[K_LR][K_LR];
    const int t = threadIdx.x;
    {
        const int k = t >> 4, kp = t & 15;
        float s = 0.f;
        #pragma unroll
        for (int r = 0; r < R_LR; ++r)
            s += Bm[r * K_LR + k] * E[r] * aa[kp * R_LR + r];
        Ms[k][kp] = s;  // M[k][k'] = sum_r B[r][k] * e[r] * aa[k'][r]
    }
    __syncthreads();
    const int d = blockIdx.x * 256 + t;
    float acc[K_LR];
    #pragma unroll
    for (int kp = 0; kp < K_LR; ++kp) acc[kp] = 0.f;
    #pragma unroll
    for (int k = 0; k < K_LR; ++k) {
        const float a = A[k * D_DIM + d];
        #pragma unroll
        for (int kp = 0; kp < K_LR; ++kp) acc[kp] = fmaf(a, Ms[k][kp], acc[kp]);
    }
    #pragma unroll
    for (int kq = 0; kq < 4; ++kq) {
        f32x4 v = { acc[kq*4+0], acc[kq*4+1], acc[kq*4+2], acc[kq*4+3] };
        *(f32x4*)(A2t + (size_t)d * K_LR + kq * 4) = v;  // A2t[d][k'] d-major
    }
}

union ShA {
    float stage[NW][ROWS][DC];   // 128 KiB, per-wave 8 KiB quadrants (phase A)
    float tred[NW][ROWS][K_LR];  // 64 KiB wave partials (after barrier)
};

__global__ void __launch_bounds__(1024) fused_kernel(const float* __restrict__ base,
                                                     const float* __restrict__ A2t,
                                                     const float* __restrict__ bb,
                                                     float* __restrict__ out, int N) {
    __shared__ ShA sh;
    __shared__ float tfin[ROWS][K_LR];        // 4 KiB final t
    const int tid  = threadIdx.x;
    const int lane = tid & 63;
    const int wv   = __builtin_amdgcn_readfirstlane(tid >> 6);
    const int r0   = blockIdx.x * ROWS;

    // ---------------- Phase A: t = rows @ A2t (barrier-free per wave) -------
    {
        const int a = lane >> 3;            // row-within-8-group for staging
        const int b = lane & 7;             // col4-group for staging
        const int d0 = wv * WWIN;
        char* wbase = (char*)&sh.stage[wv][0][0];
        const int swz_w = 16 * (b ^ a);     // swizzled 16B slot for staging write
        const int swz_r = (lane & 7) << 4;  // read-side XOR (row = lane)

        float acc[K_LR];
        #pragma unroll
        for (int k = 0; k < K_LR; ++k) acc[k] = 0.f;

        f32x4 st[8];
        #pragma unroll
        for (int i = 0; i < 8; ++i)
            st[i] = *(const f32x4*)(base + (size_t)(r0 + i*8 + a) * D_DIM + d0 + 4*b);

        for (int c = 0; c < NCH; ++c) {
            #pragma unroll
            for (int i = 0; i < 8; ++i)
                *(f32x4*)(wbase + (i*8 + a) * 128 + swz_w) = st[i];
            if (c + 1 < NCH) {
                const int dcn = d0 + (c + 1) * DC;
                #pragma unroll
                for (int i = 0; i < 8; ++i)
                    st[i] = *(const f32x4*)(base + (size_t)(r0 + i*8 + a) * D_DIM + dcn + 4*b);
            }
            const int dc = d0 + c * DC;
            #pragma unroll
            for (int j = 0; j < DC/4; ++j) {
                const f32x4 b4 = *(const f32x4*)(wbase + lane * 128 + ((16*j) ^ swz_r));
                const float* a2p = A2t + (size_t)(dc + 4*j) * K_LR;  // uniform -> s_load
                #pragma unroll
                for (int jj = 0; jj < 4; ++jj) {
                    const float bv = b4[jj];
                    #pragma unroll
                    for (int k = 0; k < K_LR; ++k)
                        acc[k] = fmaf(bv, a2p[jj * K_LR + k], acc[k]);
                }
            }
        }
        __syncthreads();   // all waves done reading their stage quadrant
        #pragma unroll
        for (int kq = 0; kq < 4; ++kq) {
            f32x4 v = { acc[kq*4+0], acc[kq*4+1], acc[kq*4+2], acc[kq*4+3] };
            *(f32x4*)(&sh.tred[wv][lane][kq * 4]) = v;   // w-major: reduce is 2-way free
        }
    }
    __syncthreads();
    // reduce 16 wave partials -> tfin (1024 threads: one (r,k) each)
    {
        const int r = tid >> 4, k = tid & 15;
        float s = 0.f;
        #pragma unroll
        for (int w = 0; w < NW; ++w)
            s += sh.tred[w][r][k];
        tfin[r][k] = s;
    }
    __syncthreads();

    // ---------------- Phase B: out = base + t @ bb.T ------------------------
    {
        const int cbase = tid * 4;            // this thread's 4 cols (covers all 4096)
        f32x4 bbr[4][4];
        #pragma unroll
        for (int q = 0; q < 4; ++q)
            #pragma unroll
            for (int kq = 0; kq < 4; ++kq)
                bbr[q][kq] = *(const f32x4*)(bb + (size_t)(cbase + q) * K_LR + kq * 4);

        #pragma unroll 2
        for (int r = 0; r < ROWS; ++r) {
            f32x4 t16[4];
            #pragma unroll
            for (int kq = 0; kq < 4; ++kq)
                t16[kq] = *(const f32x4*)(&tfin[r][kq * 4]);  // uniform broadcast

            const size_t row = (size_t)(r0 + r);
            const f32x4 bv = *(const f32x4*)(base + row * D_DIM + cbase);
            f32x4 ov;
            #pragma unroll
            for (int q = 0; q < 4; ++q) {
                float o = bv[q];
                #pragma unroll
                for (int k = 0; k < K_LR; ++k)
                    o = fmaf(t16[k >> 2][k & 3], bbr[q][k >> 2][k & 3], o);
                ov[q] = o;
            }
            __builtin_nontemporal_store(ov, (f32x4*)(out + row * D_DIM + cbase));
        }
    }
}

extern "C" void kernel_launch(void* const* d_in, const int* in_sizes, int n_in,
                              void* d_out, int out_size, void* d_ws, size_t ws_size,
                              hipStream_t stream) {
    const float* base = (const float*)d_in[0];
    const float* A    = (const float*)d_in[1];
    const float* E    = (const float*)d_in[2];
    const float* Bm   = (const float*)d_in[3];
    const float* aa   = (const float*)d_in[4];
    const float* bb   = (const float*)d_in[5];
    float* out = (float*)d_out;
    const int N = in_sizes[0] / D_DIM;  // 16384 rows

    float* A2t = (float*)d_ws;          // 256 KiB

    prep_kernel<<<D_DIM / 256, 256, 0, stream>>>(A, E, Bm, aa, A2t);
    fused_kernel<<<N / ROWS, 1024, 0, stream>>>(base, A2t, bb, out, N);
}